// Round 5
// baseline (106.450 us; speedup 1.0000x reference)
//
#include <hip/hip_runtime.h>

#define L_MAX 5
#define D_DIM 32

typedef int   vint4   __attribute__((ext_vector_type(4)));
typedef float vfloat4 __attribute__((ext_vector_type(4)));

// Kernel 1: precomp[l*E + e] = dot(edge_vector[l], edge_attr[e])
// [l][E] layout -> the wave's 5 stores are each perfectly coalesced.
// edge_attr (16 MB, single touch) is nontemporal so it doesn't evict the
// precomp table being built in L2. edge_vector read from LDS as float4.
__global__ __launch_bounds__(256) void precompute_dots_kernel(
        const float* __restrict__ edge_attr,
        const float* __restrict__ edge_vector,
        float* __restrict__ precomp, int E) {
    __shared__ vfloat4 ev4[L_MAX * (D_DIM / 4)];  // [l][c4]
    int tid = threadIdx.x;
    if (tid < L_MAX * (D_DIM / 4)) {
        const float* src = edge_vector + tid * 4;
        vfloat4 v = {src[0], src[1], src[2], src[3]};
        ev4[tid] = v;
    }
    __syncthreads();

    int e = blockIdx.x * blockDim.x + tid;
    if (e >= E) return;

    const vfloat4* row = (const vfloat4*)(edge_attr + (size_t)e * D_DIM);
    float acc[L_MAX];
#pragma unroll
    for (int l = 0; l < L_MAX; ++l) acc[l] = 0.f;

#pragma unroll
    for (int c4 = 0; c4 < D_DIM / 4; ++c4) {
        vfloat4 a = __builtin_nontemporal_load(row + c4);
#pragma unroll
        for (int l = 0; l < L_MAX; ++l) {
            vfloat4 v = ev4[l * (D_DIM / 4) + c4];
            acc[l] += v.x * a.x + v.y * a.y + v.z * a.z + v.w * a.w;
        }
    }
#pragma unroll
    for (int l = 0; l < L_MAX; ++l)
        precomp[(size_t)l * E + e] = acc[l];
}

__device__ __forceinline__ float pair_val(int e0, int e1, int e2, int e3, int e4,
                                          int len, const float* __restrict__ pc,
                                          int E) {
    float s = 0.f;
    if (len > 0) s += pc[(size_t)0 * E + e0];
    if (len > 1) s += pc[(size_t)1 * E + e1];
    if (len > 2) s += pc[(size_t)2 * E + e2];
    if (len > 3) s += pc[(size_t)3 * E + e3];
    if (len > 4) s += pc[(size_t)4 * E + e4];
    return (len > 0) ? s / (float)len : 0.f;
}

// Kernel 2: 8 pairs per thread. 10 int4 index loads + 2 int4 len loads +
// 2 float4 out stores per thread; gathers conditional (mean len = 2.5, so
// unconditional would double gather-line traffic).
__global__ __launch_bounds__(256) void path_mean8_kernel(
        const int* __restrict__ path_edges,
        const int* __restrict__ path_len,
        const float* __restrict__ precomp,
        float* __restrict__ out, int P, int E) {
    int t = blockIdx.x * blockDim.x + threadIdx.x;
    int p0 = t * 8;
    if (p0 >= P) return;

    if (p0 + 7 < P) {
        const vint4* pe4 = (const vint4*)path_edges + (size_t)t * 10;
        vint4 v0 = pe4[0], v1 = pe4[1], v2 = pe4[2], v3 = pe4[3], v4 = pe4[4];
        vint4 v5 = pe4[5], v6 = pe4[6], v7 = pe4[7], v8 = pe4[8], v9 = pe4[9];
        vint4 l0 = ((const vint4*)path_len)[t * 2 + 0];
        vint4 l1 = ((const vint4*)path_len)[t * 2 + 1];

        vfloat4 r0, r1;
        r0.x = pair_val(v0.x, v0.y, v0.z, v0.w, v1.x, l0.x, precomp, E);
        r0.y = pair_val(v1.y, v1.z, v1.w, v2.x, v2.y, l0.y, precomp, E);
        r0.z = pair_val(v2.z, v2.w, v3.x, v3.y, v3.z, l0.z, precomp, E);
        r0.w = pair_val(v3.w, v4.x, v4.y, v4.z, v4.w, l0.w, precomp, E);
        r1.x = pair_val(v5.x, v5.y, v5.z, v5.w, v6.x, l1.x, precomp, E);
        r1.y = pair_val(v6.y, v6.z, v6.w, v7.x, v7.y, l1.y, precomp, E);
        r1.z = pair_val(v7.z, v7.w, v8.x, v8.y, v8.z, l1.z, precomp, E);
        r1.w = pair_val(v8.w, v9.x, v9.y, v9.z, v9.w, l1.w, precomp, E);
        ((vfloat4*)out)[t * 2 + 0] = r0;
        ((vfloat4*)out)[t * 2 + 1] = r1;
    } else {
        for (int p = p0; p < P; ++p) {
            const int* pe = path_edges + (size_t)p * L_MAX;
            int len = path_len[p];
            out[p] = pair_val(pe[0], pe[1], pe[2], pe[3], pe[4], len, precomp, E);
        }
    }
}

// Fallback (ws too small): recompute each hop's dot directly from edge_attr.
__global__ __launch_bounds__(256) void path_mean_direct_kernel(
        const int* __restrict__ path_edges,
        const int* __restrict__ path_len,
        const float* __restrict__ edge_attr,
        const float* __restrict__ edge_vector,
        float* __restrict__ out, int P) {
    __shared__ float ev[L_MAX * D_DIM];
    int tid = threadIdx.x;
    if (tid < L_MAX * D_DIM) ev[tid] = edge_vector[tid];
    __syncthreads();

    int p = blockIdx.x * blockDim.x + tid;
    if (p >= P) return;

    int len = path_len[p];
    const int* pe = path_edges + (size_t)p * L_MAX;

    float s = 0.f;
#pragma unroll
    for (int l = 0; l < L_MAX; ++l) {
        if (l < len) {
            const float4* row = (const float4*)(edge_attr + (size_t)pe[l] * D_DIM);
            float d = 0.f;
#pragma unroll
            for (int c4 = 0; c4 < D_DIM / 4; ++c4) {
                float4 a = row[c4];
                const float* evl = ev + l * D_DIM + c4 * 4;
                d += evl[0] * a.x + evl[1] * a.y + evl[2] * a.z + evl[3] * a.w;
            }
            s += d;
        }
    }
    out[p] = (len > 0) ? s / (float)len : 0.f;
}

extern "C" void kernel_launch(void* const* d_in, const int* in_sizes, int n_in,
                              void* d_out, int out_size, void* d_ws, size_t ws_size,
                              hipStream_t stream) {
    // Inputs: x [N*D] (unused), edge_attr [E*D], edge_vector [L*D],
    // path_edges [P*L] int32, path_len [P] int32.
    const float* edge_attr   = (const float*)d_in[1];
    const float* edge_vector = (const float*)d_in[2];
    const int*   path_edges  = (const int*)d_in[3];
    const int*   path_len    = (const int*)d_in[4];
    float* out = (float*)d_out;

    const int E = in_sizes[1] / D_DIM;
    const int P = in_sizes[4];

    const size_t precomp_bytes = (size_t)E * L_MAX * sizeof(float);

    if (ws_size >= precomp_bytes) {
        float* precomp = (float*)d_ws;
        {
            int block = 256;
            int grid = (E + block - 1) / block;
            precompute_dots_kernel<<<grid, block, 0, stream>>>(edge_attr, edge_vector,
                                                               precomp, E);
        }
        {
            int block = 256;
            int threads = (P + 7) / 8;
            int grid = (threads + block - 1) / block;
            path_mean8_kernel<<<grid, block, 0, stream>>>(path_edges, path_len,
                                                          precomp, out, P, E);
        }
    } else {
        int block = 256;
        int grid = (P + block - 1) / block;
        path_mean_direct_kernel<<<grid, block, 0, stream>>>(path_edges, path_len,
                                                            edge_attr, edge_vector,
                                                            out, P);
    }
}

// Round 6
// 102.940 us; speedup vs baseline: 1.0341x; 1.0341x over previous
//
#include <hip/hip_runtime.h>

#define L_MAX 5
#define D_DIM 32

// Kernel 1: precomp[e*L + l] = dot(edge_vector[l], edge_attr[e])
// E threads, each reads one 128B row via float4 and produces 5 scalars.
// Best-measured variant (R1, 101.8 us): plain cached loads, [e][l] layout.
__global__ void precompute_dots_kernel(const float* __restrict__ edge_attr,
                                       const float* __restrict__ edge_vector,
                                       float* __restrict__ precomp, int E) {
    __shared__ float ev[L_MAX * D_DIM];
    int tid = threadIdx.x;
    if (tid < L_MAX * D_DIM) ev[tid] = edge_vector[tid];
    __syncthreads();

    int e = blockIdx.x * blockDim.x + tid;
    if (e >= E) return;

    const float4* row = (const float4*)(edge_attr + (size_t)e * D_DIM);
    float acc[L_MAX];
#pragma unroll
    for (int l = 0; l < L_MAX; ++l) acc[l] = 0.f;

#pragma unroll
    for (int c4 = 0; c4 < D_DIM / 4; ++c4) {
        float4 a = row[c4];
#pragma unroll
        for (int l = 0; l < L_MAX; ++l) {
            const float* evl = ev + l * D_DIM + c4 * 4;
            acc[l] += evl[0] * a.x + evl[1] * a.y + evl[2] * a.z + evl[3] * a.w;
        }
    }
#pragma unroll
    for (int l = 0; l < L_MAX; ++l)
        precomp[(size_t)e * L_MAX + l] = acc[l];
}

// Kernel 2: per pair p, masked mean of precomp[path_edges[p][l]*L + l] over l < len.
__global__ void path_mean_kernel(const int* __restrict__ path_edges,
                                 const int* __restrict__ path_len,
                                 const float* __restrict__ precomp,
                                 float* __restrict__ out, int P) {
    int p = blockIdx.x * blockDim.x + threadIdx.x;
    if (p >= P) return;

    int len = path_len[p];
    const int* pe = path_edges + (size_t)p * L_MAX;

    // Load all 5 indices unconditionally (always valid in [0,E)), coalesced 20B/thread.
    int e0 = pe[0], e1 = pe[1], e2 = pe[2], e3 = pe[3], e4 = pe[4];

    float s = 0.f;
    if (0 < len) s += precomp[(size_t)e0 * L_MAX + 0];
    if (1 < len) s += precomp[(size_t)e1 * L_MAX + 1];
    if (2 < len) s += precomp[(size_t)e2 * L_MAX + 2];
    if (3 < len) s += precomp[(size_t)e3 * L_MAX + 3];
    if (4 < len) s += precomp[(size_t)e4 * L_MAX + 4];

    out[p] = (len > 0) ? s / (float)len : 0.f;
}

// Fallback (ws too small): recompute each hop's dot directly from edge_attr.
__global__ void path_mean_direct_kernel(const int* __restrict__ path_edges,
                                        const int* __restrict__ path_len,
                                        const float* __restrict__ edge_attr,
                                        const float* __restrict__ edge_vector,
                                        float* __restrict__ out, int P) {
    __shared__ float ev[L_MAX * D_DIM];
    int tid = threadIdx.x;
    if (tid < L_MAX * D_DIM) ev[tid] = edge_vector[tid];
    __syncthreads();

    int p = blockIdx.x * blockDim.x + tid;
    if (p >= P) return;

    int len = path_len[p];
    const int* pe = path_edges + (size_t)p * L_MAX;

    float s = 0.f;
#pragma unroll
    for (int l = 0; l < L_MAX; ++l) {
        if (l < len) {
            const float4* row = (const float4*)(edge_attr + (size_t)pe[l] * D_DIM);
            float d = 0.f;
#pragma unroll
            for (int c4 = 0; c4 < D_DIM / 4; ++c4) {
                float4 a = row[c4];
                const float* evl = ev + l * D_DIM + c4 * 4;
                d += evl[0] * a.x + evl[1] * a.y + evl[2] * a.z + evl[3] * a.w;
            }
            s += d;
        }
    }
    out[p] = (len > 0) ? s / (float)len : 0.f;
}

extern "C" void kernel_launch(void* const* d_in, const int* in_sizes, int n_in,
                              void* d_out, int out_size, void* d_ws, size_t ws_size,
                              hipStream_t stream) {
    // Inputs: x [N*D] (unused), edge_attr [E*D], edge_vector [L*D],
    // path_edges [P*L] int32, path_len [P] int32.
    const float* edge_attr   = (const float*)d_in[1];
    const float* edge_vector = (const float*)d_in[2];
    const int*   path_edges  = (const int*)d_in[3];
    const int*   path_len    = (const int*)d_in[4];
    float* out = (float*)d_out;

    const int E = in_sizes[1] / D_DIM;
    const int P = in_sizes[4];

    const size_t precomp_bytes = (size_t)E * L_MAX * sizeof(float);

    if (ws_size >= precomp_bytes) {
        float* precomp = (float*)d_ws;
        {
            int block = 256;
            int grid = (E + block - 1) / block;
            precompute_dots_kernel<<<grid, block, 0, stream>>>(edge_attr, edge_vector,
                                                               precomp, E);
        }
        {
            int block = 256;
            int grid = (P + block - 1) / block;
            path_mean_kernel<<<grid, block, 0, stream>>>(path_edges, path_len,
                                                         precomp, out, P);
        }
    } else {
        int block = 256;
        int grid = (P + block - 1) / block;
        path_mean_direct_kernel<<<grid, block, 0, stream>>>(path_edges, path_len,
                                                            edge_attr, edge_vector,
                                                            out, P);
    }
}